// Round 10
// baseline (141.314 us; speedup 1.0000x reference)
//
#include <hip/hip_runtime.h>
#include <hip/hip_bf16.h>

#define NS_TOT 2000
#define NA 1000
#define NI 5
#define NH 32
#define SHALF 1000                 // structs per block (two blocks per atom)

typedef __attribute__((ext_vector_type(2)))  float f32x2;
typedef __attribute__((ext_vector_type(8)))  short short8;   // 8 bf16 = 4 VGPR
typedef __attribute__((ext_vector_type(16))) float f32x16;   // MFMA 32x32 acc

struct f4pair  { f32x2 a, b; };        // float4 reinterpreted as 2 pairs
struct accpair { f32x2 p[8]; };        // f32x16 reinterpreted as 8 pairs
struct pair2   { f32x2 a, b; };

// ---- VOP3P packed f32 ops with EXPLICIT op_sel/op_sel_hi ----
// R8 post-mortem: bare "v_pk_fma_f32 %0,%1,%2,%3" (modifiers omitted) gave
// wrong per-element routing (absmax 3.18; R9 with identical math in native
// ops passed -> the asm defaults were the bug). op_sel_hi:[1,1,1] +
// op_sel:[0,0,0] is the elementwise encoding: lo from lo halves, hi from hi.
__device__ __forceinline__ f32x2 pk_fma(f32x2 a, f32x2 b, f32x2 c) {
    f32x2 d;
    asm("v_pk_fma_f32 %0, %1, %2, %3 op_sel:[0,0,0] op_sel_hi:[1,1,1]"
        : "=v"(d) : "v"(a), "v"(b), "v"(c));
    return d;
}
__device__ __forceinline__ f32x2 pk_mul(f32x2 a, f32x2 b) {
    f32x2 d;
    asm("v_pk_mul_f32 %0, %1, %2 op_sel:[0,0] op_sel_hi:[1,1]"
        : "=v"(d) : "v"(a), "v"(b));
    return d;
}
__device__ __forceinline__ f32x2 pk_add(f32x2 a, f32x2 b) {
    f32x2 d;
    asm("v_pk_add_f32 %0, %1, %2 op_sel:[0,0] op_sel_hi:[1,1]"
        : "=v"(d) : "v"(a), "v"(b));
    return d;
}

// Packed Pade[5/4] tanh on a QUAD (2 pairs) with ONE v_rcp via 4-way
// reciprocal batching: q = rcp(d0*d1*d2*d3); r_i = q * (product of others).
// d in [945, ~2e8] -> product <= ~2e33 (no overflow); rel err ~3e-7.
// Per quad: 14 pk + 9 mul + 4 med3 + 1 rcp  (vs 4x(8 VALU + rcp) scalar).
__device__ __forceinline__ pair2 tanh_quad(f32x2 Xa, f32x2 Xb,
                                           f32x2 c105, f32x2 c945,
                                           f32x2 c420, f32x2 c15) {
    f32x2 za = pk_mul(Xa, Xa);
    f32x2 zb = pk_mul(Xb, Xb);
    f32x2 na = pk_fma(pk_add(za, c105), za, c945);   // z^2 + 105 z + 945
    f32x2 nb = pk_fma(pk_add(zb, c105), zb, c945);
    f32x2 da = pk_fma(pk_fma(za, c15, c420), za, c945); // 15 z^2 + 420 z + 945
    f32x2 db = pk_fma(pk_fma(zb, c15, c420), zb, c945);

    float e1 = da.x * da.y;
    float e2 = db.x * db.y;
    float q  = __builtin_amdgcn_rcpf(e1 * e2);
    float f1 = q * e2;                                // 1/(da.x*da.y)
    float f2 = q * e1;                                // 1/(db.x*db.y)
    f32x2 ra = { f1 * da.y, f1 * da.x };
    f32x2 rb = { f2 * db.y, f2 * db.x };

    pair2 out;
    out.a = pk_mul(pk_mul(Xa, na), ra);
    out.b = pk_mul(pk_mul(Xb, nb), rb);
    out.a.x = __builtin_amdgcn_fmed3f(out.a.x, -1.0f, 1.0f);
    out.a.y = __builtin_amdgcn_fmed3f(out.a.y, -1.0f, 1.0f);
    out.b.x = __builtin_amdgcn_fmed3f(out.b.x, -1.0f, 1.0f);
    out.b.y = __builtin_amdgcn_fmed3f(out.b.y, -1.0f, 1.0f);
    return out;
}

__device__ __forceinline__ float4 ffma4(float s, float4 w, float4 acc) {
    acc.x = fmaf(s, w.x, acc.x);
    acc.y = fmaf(s, w.y, acc.y);
    acc.z = fmaf(s, w.z, acc.z);
    acc.w = fmaf(s, w.w, acc.w);
    return acc;
}

__device__ __forceinline__ unsigned short f2bf_rne(float x) {
    unsigned u = __float_as_uint(x);
    unsigned r = u + 0x7FFFu + ((u >> 16) & 1u);
    return (unsigned short)(r >> 16);
}

__device__ __forceinline__ unsigned pack2(float a, float b) {
    __hip_bfloat162 p = __float22bfloat162_rn(make_float2(a, b));
    unsigned u; __builtin_memcpy(&u, &p, 4); return u;
}

__global__ __attribute__((amdgpu_flat_work_group_size(256, 256),
                          amdgpu_waves_per_eu(4, 8)))
void mlp_mfma(
    const float* __restrict__ g,
    const float* __restrict__ W1, const float* __restrict__ b1,
    const float* __restrict__ W2, const float* __restrict__ b2,
    const float* __restrict__ W3, const float* __restrict__ b3,
    float* __restrict__ out)
{
    const int bid   = blockIdx.x;
    const int araw  = bid % NA;
    const int chunk = bid / NA;              // 0 or 1: which s-half
    const int a = (araw >> 3) + 125 * (araw & 7);   // same-XCD atom swizzle
    const int t = threadIdx.x;
    const int lane = t & 63, wid = t >> 6;
    const int l31 = lane & 31, half = lane >> 5;

    const int sbase_blk = chunk * SHALF;
    const int send      = sbase_blk + SHALF;

    __shared__ __align__(16) unsigned short sW2T[NH * NH];   // W2^T bf16 [m][k]
    __shared__ __align__(16) float sB2[NH];
    __shared__ __align__(16) float sW3[NH];
    __shared__ __align__(16) unsigned short sH[4][64 * 40];  // wave-private

    for (int idx = t; idx < NH * NH; idx += 256) {
        const int i = idx >> 5, j = idx & 31;
        sW2T[j * NH + i] = f2bf_rne(W2[(size_t)a * NH * NH + idx]);
    }
    if (t < NH) { sB2[t] = b2[a * NH + t]; sW3[t] = W3[a * NH + t]; }
    __syncthreads();

    // persistent fragments
    const short8 af0 = __builtin_bit_cast(short8, *(const uint4*)(sW2T + l31 * NH + half * 8));
    const short8 af1 = __builtin_bit_cast(short8, *(const uint4*)(sW2T + l31 * NH + 16 + half * 8));
    const float4 b2q0 = ((const float4*)sB2)[0 + half];
    const float4 b2q1 = ((const float4*)sB2)[2 + half];
    const float4 b2q2 = ((const float4*)sB2)[4 + half];
    const float4 b2q3 = ((const float4*)sB2)[6 + half];
    const float4 w3q0 = ((const float4*)sW3)[0 + half];
    const float4 w3q1 = ((const float4*)sW3)[2 + half];
    const float4 w3q2 = ((const float4*)sW3)[4 + half];
    const float4 w3q3 = ((const float4*)sW3)[6 + half];
    const float bias3 = b3[a];

    // w3 as pairs (acc element pair (2r,2r+1) <-> w3 quad component pair)
    const f4pair w3p0 = __builtin_bit_cast(f4pair, w3q0);
    const f4pair w3p1 = __builtin_bit_cast(f4pair, w3q1);
    const f4pair w3p2 = __builtin_bit_cast(f4pair, w3q2);
    const f4pair w3p3 = __builtin_bit_cast(f4pair, w3q3);

    // Pade constants (VOP3P can't take literals; hoisted into VGPR pairs)
    const f32x2 c105 = {105.0f, 105.0f};
    const f32x2 c945 = {945.0f, 945.0f};
    const f32x2 c420 = {420.0f, 420.0f};
    const f32x2 c15  = {15.0f, 15.0f};

    const float4* w1v = (const float4*)(W1 + (size_t)a * NI * NH);
    const float4* b1v = (const float4*)(b1 + (size_t)a * NH);

    unsigned short* hrow = sH[wid];

    for (int it = 0; it < 4; ++it) {
        const int base = sbase_blk + it * 256 + wid * 64;
        const int s = base + lane;
        const int sl = (s < send) ? s : (send - 1);

        const float* gp = g + ((size_t)sl * NA + a) * NI;
        const float x0g = gp[0], x1g = gp[1], x2g = gp[2], x3g = gp[3], x4g = gp[4];

        // ---- layer 1: 5 -> 32 (VALU, scalar weights; SGPR operand is free) ----
        float4 h[8];
        #define INITH(q) h[q] = b1v[q];
        INITH(0) INITH(1) INITH(2) INITH(3) INITH(4) INITH(5) INITH(6) INITH(7)
        #undef INITH
        #define L1Q(i, q) h[q] = ffma4(xi, w1v[(i) * 8 + (q)], h[q]);
        #define L1I(i, xv) { const float xi = (xv); \
            L1Q(i,0) L1Q(i,1) L1Q(i,2) L1Q(i,3) L1Q(i,4) L1Q(i,5) L1Q(i,6) L1Q(i,7) }
        L1I(0, x0g) L1I(1, x1g) L1I(2, x2g) L1I(3, x3g) L1I(4, x4g)
        #undef L1I
        #undef L1Q

        // ---- tanh (packed Pade, batched rcp) on 8 quads ----
        f32x2 th[16];
        #define TH(q) { f4pair hp = __builtin_bit_cast(f4pair, h[q]); \
            pair2 r = tanh_quad(hp.a, hp.b, c105, c945, c420, c15); \
            th[2*(q)] = r.a; th[2*(q)+1] = r.b; }
        TH(0) TH(1) TH(2) TH(3) TH(4) TH(5) TH(6) TH(7)
        #undef TH

        // ---- pack bf16, stage to wave-private LDS [struct][k] ----
        uint4* wp = (uint4*)(hrow + lane * 40);
        wp[0] = make_uint4(pack2(th[0].x,th[0].y), pack2(th[1].x,th[1].y),
                           pack2(th[2].x,th[2].y), pack2(th[3].x,th[3].y));
        wp[1] = make_uint4(pack2(th[4].x,th[4].y), pack2(th[5].x,th[5].y),
                           pack2(th[6].x,th[6].y), pack2(th[7].x,th[7].y));
        wp[2] = make_uint4(pack2(th[8].x,th[8].y), pack2(th[9].x,th[9].y),
                           pack2(th[10].x,th[10].y), pack2(th[11].x,th[11].y));
        wp[3] = make_uint4(pack2(th[12].x,th[12].y), pack2(th[13].x,th[13].y),
                           pack2(th[14].x,th[14].y), pack2(th[15].x,th[15].y));
        __builtin_amdgcn_wave_barrier();

        // ---- B-fragments + MFMA ----
        const unsigned short* rb = hrow + half * 8;
        const short8 b00 = __builtin_bit_cast(short8, *(const uint4*)(rb + l31 * 40));
        const short8 b01 = __builtin_bit_cast(short8, *(const uint4*)(rb + l31 * 40 + 16));
        const short8 b10 = __builtin_bit_cast(short8, *(const uint4*)(rb + (32 + l31) * 40));
        const short8 b11 = __builtin_bit_cast(short8, *(const uint4*)(rb + (32 + l31) * 40 + 16));

        f32x16 acc0 = {b2q0.x, b2q0.y, b2q0.z, b2q0.w,
                       b2q1.x, b2q1.y, b2q1.z, b2q1.w,
                       b2q2.x, b2q2.y, b2q2.z, b2q2.w,
                       b2q3.x, b2q3.y, b2q3.z, b2q3.w};
        f32x16 acc1 = acc0;
        acc0 = __builtin_amdgcn_mfma_f32_32x32x16_bf16(af0, b00, acc0, 0, 0, 0);
        acc0 = __builtin_amdgcn_mfma_f32_32x32x16_bf16(af1, b01, acc0, 0, 0, 0);
        acc1 = __builtin_amdgcn_mfma_f32_32x32x16_bf16(af0, b10, acc1, 0, 0, 0);
        acc1 = __builtin_amdgcn_mfma_f32_32x32x16_bf16(af1, b11, acc1, 0, 0, 0);

        // ---- packed tanh (batched rcp) + packed layer-3 dot ----
        const accpair ap0 = __builtin_bit_cast(accpair, acc0);
        const accpair ap1 = __builtin_bit_cast(accpair, acc1);
        f32x2 p0 = {0.f, 0.f}, p1 = {0.f, 0.f};
        #define EPQ(r2, wa, wb) { \
            pair2 t0 = tanh_quad(ap0.p[2*(r2)], ap0.p[2*(r2)+1], c105, c945, c420, c15); \
            pair2 t1 = tanh_quad(ap1.p[2*(r2)], ap1.p[2*(r2)+1], c105, c945, c420, c15); \
            p0 = pk_fma(t0.a, (wa), p0); p0 = pk_fma(t0.b, (wb), p0); \
            p1 = pk_fma(t1.a, (wa), p1); p1 = pk_fma(t1.b, (wb), p1); }
        EPQ(0, w3p0.a, w3p0.b)
        EPQ(1, w3p1.a, w3p1.b)
        EPQ(2, w3p2.a, w3p2.b)
        EPQ(3, w3p3.a, w3p3.b)
        #undef EPQ
        float e0 = p0.x + p0.y;
        float e1 = p1.x + p1.y;
        e0 += __shfl_xor(e0, 32);
        e1 += __shfl_xor(e1, 32);

        if (lane < 32) {
            const int st0 = base + l31;
            const int st1 = base + 32 + l31;
            if (st0 < send) out[(size_t)st0 * NA + a] = e0 + bias3;
            if (st1 < send) out[(size_t)st1 * NA + a] = e1 + bias3;
        }
    }
}

extern "C" void kernel_launch(void* const* d_in, const int* in_sizes, int n_in,
                              void* d_out, int out_size, void* d_ws, size_t ws_size,
                              hipStream_t stream) {
    const float* g  = (const float*)d_in[0];
    const float* W1 = (const float*)d_in[1];
    const float* b1 = (const float*)d_in[2];
    const float* W2 = (const float*)d_in[3];
    const float* b2 = (const float*)d_in[4];
    const float* W3 = (const float*)d_in[5];
    const float* b3 = (const float*)d_in[6];
    float* out = (float*)d_out;
    mlp_mfma<<<dim3(NA * 2), dim3(256), 0, stream>>>(g, W1, b1, W2, b2, W3, b3, out);
}